// Round 10
// baseline (149.573 us; speedup 1.0000x reference)
//
#include <hip/hip_runtime.h>
#include <hip/hip_bf16.h>

#define N_NODES 50000
#define N_EDGES 600000
#define D 128
#define CAP 64        // bucket capacity; in-degree ~Poisson(12), P(>64) ~ 1e-30
#define ZSTRIDE 136   // zs row stride in bf16: 272B rows (16B-aligned), 2-way banks

typedef __attribute__((ext_vector_type(8))) short bfrag;   // 8 bf16 in 4 VGPRs
typedef __attribute__((ext_vector_type(4))) float ffrag;   // 4 f32 acc

__device__ __forceinline__ short bf16bits(float f) {
    __hip_bfloat16 h = __float2bfloat16(f);
    return *reinterpret_cast<short*>(&h);
}
__device__ __forceinline__ float bfbits2float(short b) {
    unsigned u = ((unsigned)(unsigned short)b) << 16;
    return __uint_as_float(u);
}

// cnt starts as 0xAAAAAAAA (ws poison) or 0. Normalize either base.
__device__ __forceinline__ unsigned norm_cnt(unsigned raw) {
    return raw - (raw >= 0x80000000u ? 0xAAAAAAAAu : 0u);
}

// ---- merged prep: edge fill + raw-x bf16 table + W pack ----------------
// R10 restructure: 400k threads, each with 2 conversion items (2x32B read,
// 2x16B write) and 1-2 edges (threads<200k take a second edge). Doubles
// per-CU in-flight atomic chains vs R9 (16 waves x 1.5 vs x 0.75): tests
// whether prep (budget-inferred ~30-40us) is atomic-LATENCY-bound. All
// edge chains independent; loads issued before atomics.
// xs row N_NODES = zeros (mask target). No bucket padding (fused masks).
__global__ __launch_bounds__(256, 8) void prep_kernel(
    const float* __restrict__ x, const int* __restrict__ ei,
    const float* __restrict__ W1, const float* __restrict__ W2,
    unsigned* __restrict__ cnt, unsigned short* __restrict__ srcs,
    __hip_bfloat162* __restrict__ xs, short* __restrict__ wpack)
{
    int idx = blockIdx.x * 256 + threadIdx.x;  // grid 1563*256 = 400128
    if (idx < 400000) {
        // edge loads first (up to 2 independent chains)
        int e0s = ei[idx];
        int e0d = ei[N_EDGES + idx];
        bool has2 = idx < 200000;
        int e1s = 0, e1d = 0;
        if (has2) {
            e1s = ei[400000 + idx];
            e1d = ei[N_EDGES + 400000 + idx];
        }

        // conversion loads: items idx and idx+400000 (8 floats each)
        const float4* x4 = (const float4*)x;
        float4 a0 = x4[idx * 2];
        float4 b0 = x4[idx * 2 + 1];
        float4 a1 = x4[(idx + 400000) * 2];
        float4 b1 = x4[(idx + 400000) * 2 + 1];

        // atomics: both issued before either dependent store
        unsigned s0 = norm_cnt(atomicAdd(&cnt[e0d], 1u));
        unsigned s1 = 0xFFFFFFFFu;
        if (has2) s1 = norm_cnt(atomicAdd(&cnt[e1d], 1u));
        if (s0 < CAP) srcs[e0d * CAP + s0] = (unsigned short)e0s;
        if (has2 && s1 < CAP) srcs[e1d * CAP + s1] = (unsigned short)e1s;

        bfrag o0, o1;
        o0[0] = bf16bits(a0.x); o0[1] = bf16bits(a0.y);
        o0[2] = bf16bits(a0.z); o0[3] = bf16bits(a0.w);
        o0[4] = bf16bits(b0.x); o0[5] = bf16bits(b0.y);
        o0[6] = bf16bits(b0.z); o0[7] = bf16bits(b0.w);
        o1[0] = bf16bits(a1.x); o1[1] = bf16bits(a1.y);
        o1[2] = bf16bits(a1.z); o1[3] = bf16bits(a1.w);
        o1[4] = bf16bits(b1.x); o1[5] = bf16bits(b1.y);
        o1[6] = bf16bits(b1.z); o1[7] = bf16bits(b1.w);
        ((bfrag*)xs)[idx] = o0;
        ((bfrag*)xs)[idx + 400000] = o1;
    }

    if (idx < 16) {  // zero-node row of xs (256B = 16 x 16B)
        bfrag z0;
#pragma unroll
        for (int j = 0; j < 8; ++j) z0[j] = 0;
        ((bfrag*)(xs + N_NODES * 64))[idx] = z0;
    }

    if (idx < 4096) {  // packed W: 8 bf16 per thread, 16B store
        int l  = idx & 63;
        int ks = (idx >> 6) & 3;
        int c  = (idx >> 8) & 7;
        int m  = (idx >> 11) & 1;
        int n = c * 16 + (l & 15);            // B-operand: n = lane & 15
        int kbase = ks * 32 + (l >> 4) * 8;   // B-operand: k = quad*8 + j
        const float* W = m ? W2 : W1;
        bfrag w;
#pragma unroll
        for (int j = 0; j < 8; ++j) w[j] = bf16bits(W[(kbase + j) * D + n]);
        ((bfrag*)wpack)[idx] = w;
    }
}

// ---- fused gather + z + dual MFMA GEMM + epilogue ----------------------
// BYTE-IDENTICAL to R9 (149.1us total, reproduced twice). Proven R5
// geometry: 256 threads = 4 waves, 16 nodes/block, launch_bounds(256,4)
// -> VGPR=56, no spill (R4: budget 64 spilled -> 490MB scratch; R6:
// 8-wave variant identical perf -> gather is random-line-miss-bound,
// not schedule-bound. DO NOT re-tune.)
__global__ __launch_bounds__(256, 4) void fused_kernel(
    const unsigned* __restrict__ cnt,
    const unsigned short* __restrict__ srcs,
    const __hip_bfloat162* __restrict__ xs,
    const short* __restrict__ wpack,
    const float* __restrict__ b1,
    const float* __restrict__ b2,
    float* __restrict__ out)
{
    __shared__ __align__(16) short zs16[16 * ZSTRIDE];  // bf16 z tile, 4.3 KB
    const int base = blockIdx.x * 16;
    const int t = threadIdx.x;
    const int lane = t & 63;
    const int g = t >> 6;       // wave id 0..3
    const int p = lane & 15;    // feature-octet index (8 bf16 = 16 B)
    const int q = lane >> 4;    // lane quarter -> edge slot within quad

    // ---- preload: buckets into registers, per-row params ----
    int sreg[4];
    unsigned degc[4];
    float dvr[4];
#pragma unroll
    for (int rr = 0; rr < 4; ++rr) {
        const int node = base + g * 4 + rr;
        unsigned deg = norm_cnt(cnt[node]);
        dvr[rr] = rsqrtf((float)(deg + 1));  // +1 self-loop
        degc[rr] = deg < CAP ? deg : CAP;
        sreg[rr] = (int)srcs[node * CAP + lane];  // u16 bucket, 128B coalesced
    }
    unsigned mx = 0;
#pragma unroll
    for (int rr = 0; rr < 4; ++rr) {
        unsigned n8 = (degc[rr] + 7u) & ~7u;
        mx = n8 > mx ? n8 : mx;
    }

    float acc[4][8];
#pragma unroll
    for (int rr = 0; rr < 4; ++rr)
#pragma unroll
        for (int j = 0; j < 8; ++j) acc[rr][j] = 0.f;

    // ---- time-major gather: 8x16B + 8x4B independent loads in flight ----
    for (unsigned e = 0; e < mx; e += 8) {
        int sA[4], sB[4];
        bool mA[4], mB[4];
#pragma unroll
        for (int rr = 0; rr < 4; ++rr) {
            int iA = __shfl(sreg[rr], (int)e + q, 64);
            int iB = __shfl(sreg[rr], (int)e + 4 + q, 64);
            mA[rr] = e + (unsigned)q < degc[rr];       // per-lane validity
            mB[rr] = e + 4u + (unsigned)q < degc[rr];
            sA[rr] = mA[rr] ? iA : N_NODES;            // zero row when invalid
            sB[rr] = mB[rr] ? iB : N_NODES;
        }
        // issue the small weight loads first, then the 16B gathers
        unsigned cA[4], cB[4];
#pragma unroll
        for (int rr = 0; rr < 4; ++rr) {
            cA[rr] = cnt[sA[rr]];   // 4B, L2-hot (cnt[N_NODES] readable)
            cB[rr] = cnt[sB[rr]];
        }
        bfrag v0[4], v1[4];
#pragma unroll
        for (int rr = 0; rr < 4; ++rr) {
            v0[rr] = ((const bfrag*)(xs + sA[rr] * 64))[p];
            v1[rr] = ((const bfrag*)(xs + sB[rr] * 64))[p];
        }
        float wA[4], wB[4];
#pragma unroll
        for (int rr = 0; rr < 4; ++rr) {
            wA[rr] = mA[rr] ? rsqrtf((float)(norm_cnt(cA[rr]) + 1)) : 0.f;
            wB[rr] = mB[rr] ? rsqrtf((float)(norm_cnt(cB[rr]) + 1)) : 0.f;
        }
#pragma unroll
        for (int rr = 0; rr < 4; ++rr)
#pragma unroll
            for (int j = 0; j < 8; ++j)
                acc[rr][j] += wA[rr] * bfbits2float(v0[rr][j])
                            + wB[rr] * bfbits2float(v1[rr][j]);
    }

    // ---- combine quarter partials + write z tile ----
#pragma unroll
    for (int rr = 0; rr < 4; ++rr) {
        const int r = g * 4 + rr;
#pragma unroll
        for (int j = 0; j < 8; ++j) {
            acc[rr][j] += __shfl_xor(acc[rr][j], 16, 64);
            acc[rr][j] += __shfl_xor(acc[rr][j], 32, 64);
        }
        if (q == 0) {  // 16 lanes write the 256B row
            const int node = base + r;
            bfrag vs = ((const bfrag*)(xs + node * 64))[p];  // self: raw bf16(x)
            bfrag zo;
#pragma unroll
            for (int j = 0; j < 8; ++j)
                zo[j] = bf16bits(dvr[rr] * (acc[rr][j] + dvr[rr] * bfbits2float(vs[j])));
            *(bfrag*)&zs16[r * ZSTRIDE + p * 8] = zo;
        }
    }
    __syncthreads();

    // ---- dual GEMM via MFMA 16x16x32 bf16 ----
    const int m16 = lane & 15;
    const int quad = lane >> 4;
    const int c0 = 2 * g;        // this wave's col-tiles
    const int c1 = 2 * g + 1;

    ffrag acc00 = {0.f, 0.f, 0.f, 0.f};  // W1, c0
    ffrag acc01 = {0.f, 0.f, 0.f, 0.f};  // W1, c1
    ffrag acc10 = {0.f, 0.f, 0.f, 0.f};  // W2, c0
    ffrag acc11 = {0.f, 0.f, 0.f, 0.f};  // W2, c1

#pragma unroll
    for (int ks = 0; ks < 4; ++ks) {
        // A-fragment: z[m16][ks*32 + quad*8 + j], 8 contiguous bf16 = 16 B
        bfrag a = *(const bfrag*)&zs16[m16 * ZSTRIDE + ks * 32 + quad * 8];

        bfrag b00 = *(const bfrag*)&wpack[((((0 * 8 + c0) * 4 + ks) * 64 + lane) * 8)];
        bfrag b01 = *(const bfrag*)&wpack[((((0 * 8 + c1) * 4 + ks) * 64 + lane) * 8)];
        bfrag b10 = *(const bfrag*)&wpack[((((1 * 8 + c0) * 4 + ks) * 64 + lane) * 8)];
        bfrag b11 = *(const bfrag*)&wpack[((((1 * 8 + c1) * 4 + ks) * 64 + lane) * 8)];

        acc00 = __builtin_amdgcn_mfma_f32_16x16x32_bf16(a, b00, acc00, 0, 0, 0);
        acc01 = __builtin_amdgcn_mfma_f32_16x16x32_bf16(a, b01, acc01, 0, 0, 0);
        acc10 = __builtin_amdgcn_mfma_f32_16x16x32_bf16(a, b10, acc10, 0, 0, 0);
        acc11 = __builtin_amdgcn_mfma_f32_16x16x32_bf16(a, b11, acc11, 0, 0, 0);
    }

    // ---- epilogue: C/D layout col=lane&15, row=quad*4+reg ----
    const int n0 = c0 * 16 + m16;
    const int n1 = c1 * 16 + m16;
    const float b1n0 = b1[n0], b1n1 = b1[n1];
    const float b2n0 = b2[n0], b2n1 = b2[n1];
#pragma unroll
    for (int reg = 0; reg < 4; ++reg) {
        int row = quad * 4 + reg;
        int node = base + row;
        float o0 = 0.5f * (fmaxf(acc00[reg] + b1n0, 0.f) + fmaxf(acc10[reg] + b2n0, 0.f));
        float o1 = 0.5f * (fmaxf(acc01[reg] + b1n1, 0.f) + fmaxf(acc11[reg] + b2n1, 0.f));
        out[node * D + n0] = o0;
        out[node * D + n1] = o1;
    }
}

extern "C" void kernel_launch(void* const* d_in, const int* in_sizes, int n_in,
                              void* d_out, int out_size, void* d_ws, size_t ws_size,
                              hipStream_t stream) {
    const float* x  = (const float*)d_in[0];
    const int*   ei = (const int*)d_in[1];
    const float* W1 = (const float*)d_in[2];
    const float* b1 = (const float*)d_in[3];
    const float* W2 = (const float*)d_in[4];
    const float* b2 = (const float*)d_in[5];
    float* out = (float*)d_out;

    // workspace layout (~19.5 MB)
    // cnt region 200704 B (50176 u32): index N_NODES readable for masked
    // lanes (poison there normalizes harmlessly; its weight is masked to 0
    // and its xs row is zero). srcs is u16 (6.4 MB).
    char* ws = (char*)d_ws;
    unsigned*        cnt   = (unsigned*)(ws + 0);              // 50176 u32
    unsigned short*  srcs  = (unsigned short*)(ws + 200704);   // 50000*64 u16 (6.4 MB)
    __hip_bfloat162* xs    = (__hip_bfloat162*)(ws + 6604800); // (50001)*64 bf162 (12.8 MB)
    short*           wpack = (short*)(ws + 19405056);          // 32768 bf16 (64 KB)

    prep_kernel<<<1563, 256, 0, stream>>>(x, ei, W1, W2, cnt, srcs, xs, wpack);
    fused_kernel<<<N_NODES / 16, 256, 0, stream>>>(cnt, srcs, xs, wpack, b1, b2, out);
}

// Round 11
// 148.779 us; speedup vs baseline: 1.0053x; 1.0053x over previous
//
#include <hip/hip_runtime.h>
#include <hip/hip_bf16.h>

#define N_NODES 50000
#define N_EDGES 600000
#define D 128
#define CAP 64        // bucket capacity; in-degree ~Poisson(12), P(>64) ~ 1e-30
#define ZSTRIDE 136   // zs row stride in bf16: 272B rows (16B-aligned), 2-way banks
#define CSTRIDE 16    // pcnt: one 64B line per node (atomic contention fix)

typedef __attribute__((ext_vector_type(8))) short bfrag;   // 8 bf16 in 4 VGPRs
typedef __attribute__((ext_vector_type(4))) float ffrag;   // 4 f32 acc

__device__ __forceinline__ short bf16bits(float f) {
    __hip_bfloat16 h = __float2bfloat16(f);
    return *reinterpret_cast<short*>(&h);
}
__device__ __forceinline__ float bfbits2float(short b) {
    unsigned u = ((unsigned)(unsigned short)b) << 16;
    return __uint_as_float(u);
}

// pcnt starts as 0xAAAAAAAA (ws poison) or 0. Normalize either base.
__device__ __forceinline__ unsigned norm_cnt(unsigned raw) {
    return raw - (raw >= 0x80000000u ? 0xAAAAAAAAu : 0u);
}

// ---- edge fill: histogram on LINE-PADDED counters + u16 placement ------
// R10 post-mortem: compact cnt = 3125 lines for 600k RMWs = ~192
// serialized same-line atomics per line (~40-50us floor, MLP-insensitive
// -- R10's doubled-chain experiment was exactly null). One 64B line per
// node cuts per-line serialization 16x (~12 atomics/line).
__global__ __launch_bounds__(256) void fill_kernel(
    const int* __restrict__ ei, unsigned* __restrict__ pcnt,
    unsigned short* __restrict__ srcs)
{
    int e = blockIdx.x * 256 + threadIdx.x;
    if (e < N_EDGES) {
        int s = ei[e];               // edge_index[0], < 50000 fits u16
        int d = ei[N_EDGES + e];     // edge_index[1]
        unsigned slot = norm_cnt(atomicAdd(&pcnt[d * CSTRIDE], 1u));
        if (slot < CAP) srcs[d * CAP + slot] = (unsigned short)s;
    }
}

// ---- premultiplied bf16 table + W pack (R7's proven kernel) ------------
// xs[i][f] = bf16(dinv_i * x[i][f]): weights baked in so fused's hot loop
// does zero counter reads. 800k threads x 8 floats (32B read + 16B write,
// BW-bound). Reads padded pcnt (16-thread groups broadcast one line).
// xs row N_NODES = zeros (mask target). No bucket padding (fused masks).
__global__ __launch_bounds__(256, 8) void dxw_kernel(
    const float* __restrict__ x,
    const float* __restrict__ W1, const float* __restrict__ W2,
    const unsigned* __restrict__ pcnt,
    __hip_bfloat162* __restrict__ xs, short* __restrict__ wpack)
{
    int idx = blockIdx.x * 256 + threadIdx.x;  // < 800000 exactly

    int node = idx >> 4;  // 16 threads per node (128 floats)
    unsigned deg = norm_cnt(pcnt[node * CSTRIDE]);
    float dv = rsqrtf((float)(deg + 1));  // +1 self-loop

    const float4* x4 = (const float4*)x;
    float4 a = x4[idx * 2];
    float4 b = x4[idx * 2 + 1];

    bfrag o;
    o[0] = bf16bits(dv * a.x); o[1] = bf16bits(dv * a.y);
    o[2] = bf16bits(dv * a.z); o[3] = bf16bits(dv * a.w);
    o[4] = bf16bits(dv * b.x); o[5] = bf16bits(dv * b.y);
    o[6] = bf16bits(dv * b.z); o[7] = bf16bits(dv * b.w);
    ((bfrag*)xs)[idx] = o;

    if (idx < 16) {  // zero-node row of xs (256B = 16 x 16B)
        bfrag z0;
#pragma unroll
        for (int j = 0; j < 8; ++j) z0[j] = 0;
        ((bfrag*)(xs + N_NODES * 64))[idx] = z0;
    }

    if (idx < 4096) {  // packed W: 8 bf16 per thread, 16B store
        int l  = idx & 63;
        int ks = (idx >> 6) & 3;
        int c  = (idx >> 8) & 7;
        int m  = (idx >> 11) & 1;
        int n = c * 16 + (l & 15);            // B-operand: n = lane & 15
        int kbase = ks * 32 + (l >> 4) * 8;   // B-operand: k = quad*8 + j
        const float* W = m ? W2 : W1;
        bfrag w;
#pragma unroll
        for (int j = 0; j < 8; ++j) w[j] = bf16bits(W[(kbase + j) * D + n]);
        ((bfrag*)wpack)[idx] = w;
    }
}

// ---- fused gather + z + dual MFMA GEMM + epilogue ----------------------
// R7's proven slim kernel verbatim (passed, absmax 0.0078) with deg read
// from padded pcnt (4 scattered 4B loads per wave -- negligible).
// 512 threads = 8 waves, 32 nodes/block; launch_bounds(512,2): VGPR
// budget 256 -> spills impossible (R4: budget 64 spilled -> 490MB
// scratch). Hot loop: 8 shfl + 8 masked 16B gathers + convert-add only
// (premult xs: no cnt loads, no rsqrt). Gather is random-line-bound
// (~3.4TB/s service): R5/R6/R7 schedule variants all ~45.8us. DO NOT
// re-tune the schedule.
__global__ __launch_bounds__(512, 2) void fused_kernel(
    const unsigned* __restrict__ pcnt,
    const unsigned short* __restrict__ srcs,
    const __hip_bfloat162* __restrict__ xs,
    const short* __restrict__ wpack,
    const float* __restrict__ b1,
    const float* __restrict__ b2,
    float* __restrict__ out)
{
    __shared__ __align__(16) short zs16[32 * ZSTRIDE];  // bf16 z tile, 8.7 KB
    const int base = blockIdx.x * 32;
    const int t = threadIdx.x;
    const int lane = t & 63;
    const int g = t >> 6;       // wave id 0..7
    const int rg = g >> 2;      // row-group 0..1 (16 rows each)
    const int gc = g & 3;       // col-pair id 0..3
    const int p = lane & 15;    // feature-octet index (8 bf16 = 16 B)
    const int q = lane >> 4;    // lane quarter -> edge slot within quad

    // ---- preload: buckets into registers, per-row params, self rows ----
    int sreg[4];
    unsigned degc[4];
    float dvr[4];
    bfrag vself[4];
#pragma unroll
    for (int rr = 0; rr < 4; ++rr) {
        const int node = base + rg * 16 + gc * 4 + rr;
        unsigned deg = norm_cnt(pcnt[node * CSTRIDE]);  // phantom: poison -> 0
        dvr[rr] = rsqrtf((float)(deg + 1));   // +1 self-loop
        degc[rr] = deg < CAP ? deg : CAP;
        sreg[rr] = (int)srcs[node * CAP + lane];            // 128B coalesced
        vself[rr] = ((const bfrag*)(xs + node * 64))[p];    // self: dinv*x
    }
    unsigned mx = 0;
#pragma unroll
    for (int rr = 0; rr < 4; ++rr) {
        unsigned n8 = (degc[rr] + 7u) & ~7u;
        mx = n8 > mx ? n8 : mx;
    }

    float acc[4][8];
#pragma unroll
    for (int rr = 0; rr < 4; ++rr)
#pragma unroll
        for (int j = 0; j < 8; ++j) acc[rr][j] = 0.f;

    // ---- time-major gather: 8 independent 16B gathers in flight/step ----
    for (unsigned e = 0; e < mx; e += 8) {
        int sA[4], sB[4];
#pragma unroll
        for (int rr = 0; rr < 4; ++rr) {
            int iA = __shfl(sreg[rr], (int)e + q, 64);
            int iB = __shfl(sreg[rr], (int)e + 4 + q, 64);
            sA[rr] = (e + (unsigned)q < degc[rr]) ? iA : N_NODES;
            sB[rr] = (e + 4u + (unsigned)q < degc[rr]) ? iB : N_NODES;
        }
        bfrag v0[4], v1[4];
#pragma unroll
        for (int rr = 0; rr < 4; ++rr) {
            v0[rr] = ((const bfrag*)(xs + sA[rr] * 64))[p];
            v1[rr] = ((const bfrag*)(xs + sB[rr] * 64))[p];
        }
#pragma unroll
        for (int rr = 0; rr < 4; ++rr)
#pragma unroll
            for (int j = 0; j < 8; ++j)
                acc[rr][j] += bfbits2float(v0[rr][j]) + bfbits2float(v1[rr][j]);
    }

    // ---- combine quarter partials + write z tile ----
#pragma unroll
    for (int rr = 0; rr < 4; ++rr) {
        const int r = rg * 16 + gc * 4 + rr;
#pragma unroll
        for (int j = 0; j < 8; ++j) {
            acc[rr][j] += __shfl_xor(acc[rr][j], 16, 64);
            acc[rr][j] += __shfl_xor(acc[rr][j], 32, 64);
        }
        if (q == 0) {  // 16 lanes write the 256B row
            bfrag zo;
#pragma unroll
            for (int j = 0; j < 8; ++j)
                zo[j] = bf16bits(dvr[rr] * (acc[rr][j] + bfbits2float(vself[rr][j])));
            *(bfrag*)&zs16[r * ZSTRIDE + p * 8] = zo;
        }
    }
    __syncthreads();

    // ---- dual GEMM via MFMA 16x16x32 bf16 ----
    // wave g: A rows rg*16..rg*16+15, col-tiles {2*gc, 2*gc+1} x {W1,W2}
    const int m16 = lane & 15;
    const int quad = lane >> 4;
    const int c0 = 2 * gc;
    const int c1 = 2 * gc + 1;

    ffrag acc00 = {0.f, 0.f, 0.f, 0.f};  // W1, c0
    ffrag acc01 = {0.f, 0.f, 0.f, 0.f};  // W1, c1
    ffrag acc10 = {0.f, 0.f, 0.f, 0.f};  // W2, c0
    ffrag acc11 = {0.f, 0.f, 0.f, 0.f};  // W2, c1

#pragma unroll
    for (int ks = 0; ks < 4; ++ks) {
        // A-fragment: z[rg*16+m16][ks*32 + quad*8 + j], 8 contiguous bf16
        bfrag a = *(const bfrag*)&zs16[(rg * 16 + m16) * ZSTRIDE + ks * 32 + quad * 8];

        bfrag b00 = *(const bfrag*)&wpack[((((0 * 8 + c0) * 4 + ks) * 64 + lane) * 8)];
        bfrag b01 = *(const bfrag*)&wpack[((((0 * 8 + c1) * 4 + ks) * 64 + lane) * 8)];
        bfrag b10 = *(const bfrag*)&wpack[((((1 * 8 + c0) * 4 + ks) * 64 + lane) * 8)];
        bfrag b11 = *(const bfrag*)&wpack[((((1 * 8 + c1) * 4 + ks) * 64 + lane) * 8)];

        acc00 = __builtin_amdgcn_mfma_f32_16x16x32_bf16(a, b00, acc00, 0, 0, 0);
        acc01 = __builtin_amdgcn_mfma_f32_16x16x32_bf16(a, b01, acc01, 0, 0, 0);
        acc10 = __builtin_amdgcn_mfma_f32_16x16x32_bf16(a, b10, acc10, 0, 0, 0);
        acc11 = __builtin_amdgcn_mfma_f32_16x16x32_bf16(a, b11, acc11, 0, 0, 0);
    }

    // ---- epilogue: C/D layout col=lane&15, row=quad*4+reg ----
    const int n0 = c0 * 16 + m16;
    const int n1 = c1 * 16 + m16;
    const float b1n0 = b1[n0], b1n1 = b1[n1];
    const float b2n0 = b2[n0], b2n1 = b2[n1];
#pragma unroll
    for (int reg = 0; reg < 4; ++reg) {
        int row = rg * 16 + quad * 4 + reg;
        int node = base + row;
        if (node < N_NODES) {  // last block: phantom rows not stored
            float o0 = 0.5f * (fmaxf(acc00[reg] + b1n0, 0.f) + fmaxf(acc10[reg] + b2n0, 0.f));
            float o1 = 0.5f * (fmaxf(acc01[reg] + b1n1, 0.f) + fmaxf(acc11[reg] + b2n1, 0.f));
            out[node * D + n0] = o0;
            out[node * D + n1] = o1;
        }
    }
}

extern "C" void kernel_launch(void* const* d_in, const int* in_sizes, int n_in,
                              void* d_out, int out_size, void* d_ws, size_t ws_size,
                              hipStream_t stream) {
    const float* x  = (const float*)d_in[0];
    const int*   ei = (const int*)d_in[1];
    const float* W1 = (const float*)d_in[2];
    const float* b1 = (const float*)d_in[3];
    const float* W2 = (const float*)d_in[4];
    const float* b2 = (const float*)d_in[5];
    float* out = (float*)d_out;

    // workspace layout (~22.5 MB)
    // pcnt: 64B-line-padded counters (atomic contention fix); phantom-node
    // reads (nodes 50000-50015) stay inside its 3.21MB region, poison
    // normalizes to deg=0. srcs u16; fused's phantom srcs/xs over-reads
    // land in the following ws regions (garbage, fully masked / unstored).
    char* ws = (char*)d_ws;
    unsigned*        pcnt  = (unsigned*)(ws + 0);               // 50176*16 u32 (3.21 MB)
    unsigned short*  srcs  = (unsigned short*)(ws + 3211264);   // 50000*64 u16 (6.4 MB)
    __hip_bfloat162* xs    = (__hip_bfloat162*)(ws + 9611264);  // (50001)*64 bf162 (12.8 MB)
    short*           wpack = (short*)(ws + 22411520);           // 32768 bf16 (64 KB)

    fill_kernel<<<(N_EDGES + 255) / 256, 256, 0, stream>>>(ei, pcnt, srcs);
    dxw_kernel<<<3125, 256, 0, stream>>>(x, W1, W2, pcnt, xs, wpack);
    fused_kernel<<<(N_NODES + 31) / 32, 512, 0, stream>>>(pcnt, srcs, xs, wpack, b1, b2, out);
}